// Round 1
// baseline (610.938 us; speedup 1.0000x reference)
//
#include <hip/hip_runtime.h>
#include <cstddef>

#define B_ 8
#define N_ 1024
#define C_ 512
#define H_ 8
#define DH_ 64
#define QKVLD 1536
#define SCALE_ 0.125f
#define NEG_ -1.0e9f

// ---------------------------------------------------------------------------
// Generic fp32 GEMM: C[M,Nn] = A[M,K] * Bt[Nn,K]^T + bias
// 64x64 tile, BK=16, 256 threads, 4x4 microtile. M,Nn mult of 64, K mult of 16.
// ---------------------------------------------------------------------------
__global__ __launch_bounds__(256) void gemm_abt(
    const float* __restrict__ A, int lda,
    const float* __restrict__ Bt, int ldb,
    const float* __restrict__ bias,
    float* __restrict__ C, int ldc,
    int M, int Nn, int K)
{
    __shared__ float As[16][64];
    __shared__ float Bs[16][64];
    const int tid = threadIdx.x;
    const int bm = blockIdx.y * 64;
    const int bn = blockIdx.x * 64;
    const int tx = tid & 15, ty = tid >> 4;
    const int lr = tid >> 2;            // 0..63 row in tile
    const int lc = (tid & 3) << 2;      // 0,4,8,12 col in BK
    float acc[4][4] = {};
    for (int k0 = 0; k0 < K; k0 += 16) {
        float4 av = *(const float4*)(A  + (size_t)(bm + lr) * lda + k0 + lc);
        float4 bv = *(const float4*)(Bt + (size_t)(bn + lr) * ldb + k0 + lc);
        __syncthreads();
        As[lc+0][lr] = av.x; As[lc+1][lr] = av.y; As[lc+2][lr] = av.z; As[lc+3][lr] = av.w;
        Bs[lc+0][lr] = bv.x; Bs[lc+1][lr] = bv.y; Bs[lc+2][lr] = bv.z; Bs[lc+3][lr] = bv.w;
        __syncthreads();
#pragma unroll
        for (int k = 0; k < 16; ++k) {
            const float4 a  = *(const float4*)&As[k][ty << 2];
            const float4 bb = *(const float4*)&Bs[k][tx << 2];
            const float ar[4] = {a.x, a.y, a.z, a.w};
            const float br[4] = {bb.x, bb.y, bb.z, bb.w};
#pragma unroll
            for (int i = 0; i < 4; ++i)
#pragma unroll
                for (int j = 0; j < 4; ++j)
                    acc[i][j] = fmaf(ar[i], br[j], acc[i][j]);
        }
    }
    float4 bias4 = make_float4(0.f, 0.f, 0.f, 0.f);
    if (bias) bias4 = *(const float4*)(bias + bn + (tx << 2));
#pragma unroll
    for (int i = 0; i < 4; ++i) {
        float4 r;
        r.x = acc[i][0] + bias4.x;
        r.y = acc[i][1] + bias4.y;
        r.z = acc[i][2] + bias4.z;
        r.w = acc[i][3] + bias4.w;
        *(float4*)(C + (size_t)(bm + (ty << 2) + i) * ldc + bn + (tx << 2)) = r;
    }
}

// ---------------------------------------------------------------------------
// Scores: S[b,h,n,m] = SCALE * sum_d Q[b,n,h,d] * K[b,m,h,d]
// Q,K live in qkv buffer [B,N,3,H,DH]. Batched over z = b*8+h.
// ---------------------------------------------------------------------------
__global__ __launch_bounds__(256) void scores_kernel(
    const float* __restrict__ qkv, float* __restrict__ S)
{
    const int z = blockIdx.z, b = z >> 3, h = z & 7;
    const float* Q  = qkv + (size_t)b * N_ * QKVLD + h * DH_;        // [n][d] ld 1536
    const float* Kp = Q + C_;                                         // [m][d] ld 1536
    float* Sp = S + (size_t)z * N_ * N_;
    __shared__ float As[16][64];
    __shared__ float Bs[16][64];
    const int tid = threadIdx.x;
    const int bm = blockIdx.y * 64;
    const int bn = blockIdx.x * 64;
    const int tx = tid & 15, ty = tid >> 4;
    const int lr = tid >> 2;
    const int lc = (tid & 3) << 2;
    float acc[4][4] = {};
    for (int k0 = 0; k0 < DH_; k0 += 16) {
        float4 av = *(const float4*)(Q  + (size_t)(bm + lr) * QKVLD + k0 + lc);
        float4 bv = *(const float4*)(Kp + (size_t)(bn + lr) * QKVLD + k0 + lc);
        __syncthreads();
        As[lc+0][lr] = av.x; As[lc+1][lr] = av.y; As[lc+2][lr] = av.z; As[lc+3][lr] = av.w;
        Bs[lc+0][lr] = bv.x; Bs[lc+1][lr] = bv.y; Bs[lc+2][lr] = bv.z; Bs[lc+3][lr] = bv.w;
        __syncthreads();
#pragma unroll
        for (int k = 0; k < 16; ++k) {
            const float4 a  = *(const float4*)&As[k][ty << 2];
            const float4 bb = *(const float4*)&Bs[k][tx << 2];
            const float ar[4] = {a.x, a.y, a.z, a.w};
            const float br[4] = {bb.x, bb.y, bb.z, bb.w};
#pragma unroll
            for (int i = 0; i < 4; ++i)
#pragma unroll
                for (int j = 0; j < 4; ++j)
                    acc[i][j] = fmaf(ar[i], br[j], acc[i][j]);
        }
    }
#pragma unroll
    for (int i = 0; i < 4; ++i) {
        float4 r;
        r.x = acc[i][0] * SCALE_;
        r.y = acc[i][1] * SCALE_;
        r.z = acc[i][2] * SCALE_;
        r.w = acc[i][3] * SCALE_;
        *(float4*)(Sp + (size_t)(bm + (ty << 2) + i) * N_ + bn + (tx << 2)) = r;
    }
}

// ---------------------------------------------------------------------------
// Per (b,n): pre-mix (pl) + bias + mask + softmax + post-mix (pw), in-place on
// the attn buffer. 256 threads, each owns 4 key columns (m = tid*4..+3), so
// all 8 heads of its columns live in registers -> head-mixing is register-only.
// ---------------------------------------------------------------------------
__global__ __launch_bounds__(256) void mix_softmax_kernel(
    float* __restrict__ attn, const float* __restrict__ mask,
    const float* __restrict__ pl_w, const float* __restrict__ pl_b,
    const float* __restrict__ pw_w, const float* __restrict__ pw_b)
{
    const int n = blockIdx.x;
    const int b = blockIdx.y;
    const int tid = threadIdx.x;
    __shared__ float w1[64], w2[64], b1[8], b2[8];
    __shared__ float red[4][8];
    if (tid < 64) w1[tid] = pl_w[tid];
    else if (tid < 128) w2[tid - 64] = pw_w[tid - 64];
    else if (tid < 136) b1[tid - 128] = pl_b[tid - 128];
    else if (tid < 144) b2[tid - 136] = pw_b[tid - 136];
    __syncthreads();

    const int m0 = tid << 2;
    const size_t rowbase = ((size_t)(b * H_) * N_ + n) * N_ + m0;   // h=0 row
    const size_t hstride = (size_t)N_ * N_;

    float s[8][4];
#pragma unroll
    for (int h = 0; h < 8; ++h) {
        float4 v = *(const float4*)(attn + rowbase + (size_t)h * hstride);
        s[h][0] = v.x; s[h][1] = v.y; s[h][2] = v.z; s[h][3] = v.w;
    }
    float4 mv = *(const float4*)(mask + b * N_ + m0);
    const float mk[4] = {(1.f - mv.x) * NEG_, (1.f - mv.y) * NEG_,
                         (1.f - mv.z) * NEG_, (1.f - mv.w) * NEG_};
    float a[8][4];
#pragma unroll
    for (int g = 0; g < 8; ++g)
#pragma unroll
        for (int j = 0; j < 4; ++j) a[g][j] = b1[g] + mk[j];
#pragma unroll
    for (int h = 0; h < 8; ++h)
#pragma unroll
        for (int g = 0; g < 8; ++g) {
            const float w = w1[g * 8 + h];
#pragma unroll
            for (int j = 0; j < 4; ++j) a[g][j] = fmaf(w, s[h][j], a[g][j]);
        }
    // softmax per row g over 1024 columns
    float mx[8];
#pragma unroll
    for (int g = 0; g < 8; ++g)
        mx[g] = fmaxf(fmaxf(a[g][0], a[g][1]), fmaxf(a[g][2], a[g][3]));
#pragma unroll
    for (int g = 0; g < 8; ++g)
        for (int off = 32; off; off >>= 1)
            mx[g] = fmaxf(mx[g], __shfl_xor(mx[g], off));
    const int wv = tid >> 6, ln = tid & 63;
    if (ln == 0) {
#pragma unroll
        for (int g = 0; g < 8; ++g) red[wv][g] = mx[g];
    }
    __syncthreads();
#pragma unroll
    for (int g = 0; g < 8; ++g)
        mx[g] = fmaxf(fmaxf(red[0][g], red[1][g]), fmaxf(red[2][g], red[3][g]));
    __syncthreads();
    float sm[8];
#pragma unroll
    for (int g = 0; g < 8; ++g) {
        float t = 0.f;
#pragma unroll
        for (int j = 0; j < 4; ++j) {
            a[g][j] = __expf(a[g][j] - mx[g]);
            t += a[g][j];
        }
        sm[g] = t;
    }
#pragma unroll
    for (int g = 0; g < 8; ++g)
        for (int off = 32; off; off >>= 1)
            sm[g] += __shfl_xor(sm[g], off);
    if (ln == 0) {
#pragma unroll
        for (int g = 0; g < 8; ++g) red[wv][g] = sm[g];
    }
    __syncthreads();
#pragma unroll
    for (int g = 0; g < 8; ++g) {
        const float inv = 1.f / (red[0][g] + red[1][g] + red[2][g] + red[3][g]);
#pragma unroll
        for (int j = 0; j < 4; ++j) a[g][j] *= inv;
    }
    // post-mix + write back (in place)
#pragma unroll
    for (int g = 0; g < 8; ++g) {
        float o[4] = {b2[g], b2[g], b2[g], b2[g]};
#pragma unroll
        for (int h = 0; h < 8; ++h) {
            const float w = w2[g * 8 + h];
#pragma unroll
            for (int j = 0; j < 4; ++j) o[j] = fmaf(w, a[h][j], o[j]);
        }
        *(float4*)(attn + rowbase + (size_t)g * hstride) = make_float4(o[0], o[1], o[2], o[3]);
    }
}

// ---------------------------------------------------------------------------
// PV: out1[b,n,h*64+d] = sum_m attn2[b,h,n,m] * V[b,m,h,d]
// Batched over z = b*8+h. A = attn2 (ld 1024), B = V (ld 1536, non-transposed).
// ---------------------------------------------------------------------------
__global__ __launch_bounds__(256) void pv_kernel(
    const float* __restrict__ attn, const float* __restrict__ qkv,
    float* __restrict__ out1)
{
    const int z = blockIdx.z, b = z >> 3, h = z & 7;
    const float* A = attn + (size_t)z * N_ * N_;
    const float* V = qkv + (size_t)b * N_ * QKVLD + 2 * C_ + h * DH_;
    float* C = out1 + (size_t)b * N_ * C_ + h * DH_;
    const int bm = blockIdx.y * 64;
    __shared__ float As[16][64];
    __shared__ float Bs[16][64];
    const int tid = threadIdx.x;
    const int tx = tid & 15, ty = tid >> 4;
    const int lr = tid >> 2, lc = (tid & 3) << 2;     // A loader
    const int br = tid >> 4, bc = (tid & 15) << 2;    // B loader
    float acc[4][4] = {};
    for (int k0 = 0; k0 < N_; k0 += 16) {
        float4 av = *(const float4*)(A + (size_t)(bm + lr) * N_ + k0 + lc);
        float4 bv = *(const float4*)(V + (size_t)(k0 + br) * QKVLD + bc);
        __syncthreads();
        As[lc+0][lr] = av.x; As[lc+1][lr] = av.y; As[lc+2][lr] = av.z; As[lc+3][lr] = av.w;
        *(float4*)&Bs[br][bc] = bv;
        __syncthreads();
#pragma unroll
        for (int k = 0; k < 16; ++k) {
            const float4 a  = *(const float4*)&As[k][ty << 2];
            const float4 bb = *(const float4*)&Bs[k][tx << 2];
            const float ar[4] = {a.x, a.y, a.z, a.w};
            const float br4[4] = {bb.x, bb.y, bb.z, bb.w};
#pragma unroll
            for (int i = 0; i < 4; ++i)
#pragma unroll
                for (int j = 0; j < 4; ++j)
                    acc[i][j] = fmaf(ar[i], br4[j], acc[i][j]);
        }
    }
#pragma unroll
    for (int i = 0; i < 4; ++i) {
        *(float4*)(C + (size_t)(bm + (ty << 2) + i) * C_ + (tx << 2)) =
            make_float4(acc[i][0], acc[i][1], acc[i][2], acc[i][3]);
    }
}

extern "C" void kernel_launch(void* const* d_in, const int* in_sizes, int n_in,
                              void* d_out, int out_size, void* d_ws, size_t ws_size,
                              hipStream_t stream)
{
    const float* x      = (const float*)d_in[0];
    const float* mask   = (const float*)d_in[1];
    const float* qkv_w  = (const float*)d_in[2];
    const float* qkv_b  = (const float*)d_in[3];
    const float* proj_w = (const float*)d_in[4];
    const float* proj_b = (const float*)d_in[5];
    const float* pl_w   = (const float*)d_in[6];
    const float* pl_b   = (const float*)d_in[7];
    const float* pw_w   = (const float*)d_in[8];
    const float* pw_b   = (const float*)d_in[9];

    float* out  = (float*)d_out;                       // [B,N,C] = 4,194,304 f
    float* attn = out + (size_t)B_ * N_ * C_;          // [B,H,N,N] = 67,108,864 f
    float* qkv  = (float*)d_ws;                        // [B,N,3C] = 12,582,912 f (50.3 MB)
    float* out1 = qkv + (size_t)B_ * N_ * 3 * C_;      // [B,N,C]  =  4,194,304 f (16.8 MB)
    (void)in_sizes; (void)n_in; (void)out_size; (void)ws_size;

    // 1) qkv = x @ qkv_w^T + qkv_b      (8192 x 1536 x 512)
    gemm_abt<<<dim3(3 * C_ / 64, B_ * N_ / 64), 256, 0, stream>>>(
        x, C_, qkv_w, C_, qkv_b, qkv, 3 * C_, B_ * N_, 3 * C_, C_);

    // 2) raw scaled scores into d_out's attn region (used as scratch)
    scores_kernel<<<dim3(N_ / 64, N_ / 64, B_ * H_), 256, 0, stream>>>(qkv, attn);

    // 3) pre-mix + mask + softmax + post-mix, in place
    mix_softmax_kernel<<<dim3(N_, B_), 256, 0, stream>>>(attn, mask, pl_w, pl_b, pw_w, pw_b);

    // 4) out1 = attn2 @ V   (per b,h; out1 laid out [b,n,h,d])
    pv_kernel<<<dim3(1, N_ / 64, B_ * H_), 256, 0, stream>>>(attn, qkv, out1);

    // 5) out = out1 @ proj_w^T + proj_b (8192 x 512 x 512)
    gemm_abt<<<dim3(C_ / 64, B_ * N_ / 64), 256, 0, stream>>>(
        out1, C_, proj_w, C_, proj_b, out, C_, B_ * N_, C_, C_);
}

// Round 2
// 318.211 us; speedup vs baseline: 1.9199x; 1.9199x over previous
//
#include <hip/hip_runtime.h>
#include <cstddef>

#define B_ 8
#define N_ 1024
#define C_ 512
#define H_ 8
#define DH_ 64
#define QKVLD 1536
#define SCALE_ 0.125f
#define NEG_ -1.0e9f

typedef _Float16 f16;
typedef f16  f16x4 __attribute__((ext_vector_type(4)));
typedef f16  f16x8 __attribute__((ext_vector_type(8)));
typedef float f32x4 __attribute__((ext_vector_type(4)));

static __device__ __forceinline__ f16x4 cvt4(float4 v) {
    f16x4 r; r[0] = (f16)v.x; r[1] = (f16)v.y; r[2] = (f16)v.z; r[3] = (f16)v.w;
    return r;
}

// ---------------------------------------------------------------------------
// Core: C[128 x BN] tile of  A(fp32)[M,K] * B^T + bias, f16 MFMA 16x16x32.
// B side: BF16HALF ? f16 Bt[N,K] (direct)  :  fp32 Bt[N,K] (convert on stage).
// 256 threads = 4 waves (2x2), wave tile 64 x BN/2, frags 4 x (BN/32).
// LDS rows padded to 40 halfs (80B stride -> 2-way bank alias = free).
// ---------------------------------------------------------------------------
template<int BN, bool BHALF>
__device__ __forceinline__ void gemm_core(
    const float* __restrict__ A, int lda,
    const void* __restrict__ Bv, int ldb,
    const float* __restrict__ bias, float scale,
    float* __restrict__ Cc, int ldc, int K, int bm, int bn)
{
    constexpr int FJ = BN / 32;
    __shared__ __align__(16) f16 Af[128][40];
    __shared__ __align__(16) f16 Bf[BN][40];
    const int tid  = threadIdx.x;
    const int wid  = tid >> 6, lane = tid & 63;
    const int wm   = (wid >> 1) * 64, wn = (wid & 1) * (BN / 2);
    const int lrow = lane & 15, kg = lane >> 4;
    const int ar = tid >> 3, ac = (tid & 7) << 2;     // fp32 stager: 32 rows/iter
    const int hr = tid >> 2, hc = (tid & 3) << 3;     // f16 stager (BN=64)

    f32x4 acc[4][FJ];
#pragma unroll
    for (int i = 0; i < 4; ++i)
#pragma unroll
        for (int j = 0; j < FJ; ++j) acc[i][j] = (f32x4){0.f, 0.f, 0.f, 0.f};

    for (int k0 = 0; k0 < K; k0 += 32) {
        float4 a0 = *(const float4*)(A + (size_t)(bm + ar     ) * lda + k0 + ac);
        float4 a1 = *(const float4*)(A + (size_t)(bm + ar + 32) * lda + k0 + ac);
        float4 a2 = *(const float4*)(A + (size_t)(bm + ar + 64) * lda + k0 + ac);
        float4 a3 = *(const float4*)(A + (size_t)(bm + ar + 96) * lda + k0 + ac);
        float4 b0, b1, b2, b3;
        f16x8  bh;
        if constexpr (!BHALF) {
            const float* Bp = (const float*)Bv;
            b0 = *(const float4*)(Bp + (size_t)(bn + ar     ) * ldb + k0 + ac);
            b1 = *(const float4*)(Bp + (size_t)(bn + ar + 32) * ldb + k0 + ac);
            if constexpr (BN == 128) {
                b2 = *(const float4*)(Bp + (size_t)(bn + ar + 64) * ldb + k0 + ac);
                b3 = *(const float4*)(Bp + (size_t)(bn + ar + 96) * ldb + k0 + ac);
            }
        } else {
            const f16* Bp = (const f16*)Bv;   // BN==64: 64 rows x 32 halfs, 1 ld/thread
            bh = *(const f16x8*)(Bp + (size_t)(bn + hr) * ldb + k0 + hc);
        }
        __syncthreads();
        *(f16x4*)&Af[ar     ][ac] = cvt4(a0);
        *(f16x4*)&Af[ar + 32][ac] = cvt4(a1);
        *(f16x4*)&Af[ar + 64][ac] = cvt4(a2);
        *(f16x4*)&Af[ar + 96][ac] = cvt4(a3);
        if constexpr (!BHALF) {
            *(f16x4*)&Bf[ar     ][ac] = cvt4(b0);
            *(f16x4*)&Bf[ar + 32][ac] = cvt4(b1);
            if constexpr (BN == 128) {
                *(f16x4*)&Bf[ar + 64][ac] = cvt4(b2);
                *(f16x4*)&Bf[ar + 96][ac] = cvt4(b3);
            }
        } else {
            *(f16x8*)&Bf[hr][hc] = bh;
        }
        __syncthreads();
        f16x8 af[4], bf[FJ];
#pragma unroll
        for (int i = 0; i < 4; ++i)
            af[i] = *(const f16x8*)&Af[wm + i * 16 + lrow][kg * 8];
#pragma unroll
        for (int j = 0; j < FJ; ++j)
            bf[j] = *(const f16x8*)&Bf[wn + j * 16 + lrow][kg * 8];
#pragma unroll
        for (int i = 0; i < 4; ++i)
#pragma unroll
            for (int j = 0; j < FJ; ++j)
                acc[i][j] = __builtin_amdgcn_mfma_f32_16x16x32_f16(af[i], bf[j], acc[i][j], 0, 0, 0);
    }
#pragma unroll
    for (int j = 0; j < FJ; ++j) {
        const int col = bn + wn + j * 16 + lrow;
        const float bv = bias ? bias[col] : 0.f;
#pragma unroll
        for (int i = 0; i < 4; ++i) {
            const int row0 = bm + wm + i * 16 + kg * 4;
#pragma unroll
            for (int r = 0; r < 4; ++r)
                Cc[(size_t)(row0 + r) * ldc + col] = acc[i][j][r] * scale + bv;
        }
    }
}

__global__ __launch_bounds__(256) void k_qkv(const float* __restrict__ x,
                                             const float* __restrict__ w,
                                             const float* __restrict__ b,
                                             float* __restrict__ o) {
    gemm_core<128, false>(x, C_, w, C_, b, 1.f, o, QKVLD, C_,
                          blockIdx.y * 128, blockIdx.x * 128);
}

__global__ __launch_bounds__(256) void k_proj(const float* __restrict__ o1,
                                              const float* __restrict__ w,
                                              const float* __restrict__ b,
                                              float* __restrict__ o) {
    gemm_core<128, false>(o1, C_, w, C_, b, 1.f, o, C_, C_,
                          blockIdx.y * 128, blockIdx.x * 128);
}

__global__ __launch_bounds__(256) void k_scores(const float* __restrict__ qkv,
                                                float* __restrict__ attn) {
    const int z = blockIdx.z, b = z >> 3, h = z & 7;
    const float* Q  = qkv + (size_t)b * N_ * QKVLD + h * DH_;
    const float* Kp = Q + C_;
    gemm_core<128, false>(Q, QKVLD, Kp, QKVLD, nullptr, SCALE_,
                          attn + (size_t)z * N_ * N_, N_, DH_,
                          blockIdx.y * 128, blockIdx.x * 128);
}

__global__ __launch_bounds__(256) void k_pv(const float* __restrict__ attn,
                                            const f16* __restrict__ vt,
                                            float* __restrict__ out1) {
    const int z = blockIdx.z, b = z >> 3, h = z & 7;
    gemm_core<64, true>(attn + (size_t)z * N_ * N_, N_,
                        vt + (size_t)z * DH_ * N_, N_, nullptr, 1.f,
                        out1 + (size_t)b * N_ * C_ + h * DH_, C_, N_,
                        blockIdx.y * 128, 0);
}

// ---------------------------------------------------------------------------
// VT16[b][h][d][m] (f16) = qkv V part [b][m][2C + h*64 + d], LDS-tiled transpose.
// grid = 64 (b*8+h), 256 threads, 16 m-tiles of 64x64.
// ---------------------------------------------------------------------------
__global__ __launch_bounds__(256) void pack_vt(const float* __restrict__ qkv,
                                               f16* __restrict__ vt) {
    const int z = blockIdx.x, b = z >> 3, h = z & 7;
    const float* V = qkv + (size_t)b * N_ * QKVLD + 2 * C_ + h * DH_;
    f16* O = vt + (size_t)z * DH_ * N_;
    __shared__ __align__(16) f16 T[64][72];
    const int t = threadIdx.x;
    for (int m0 = 0; m0 < N_; m0 += 64) {
#pragma unroll
        for (int it = 0; it < 4; ++it) {
            const int m = (t >> 4) + it * 16, dg = t & 15, d = dg * 4;
            float4 v = *(const float4*)(V + (size_t)(m0 + m) * QKVLD + d);
            T[d + 0][m] = (f16)v.x; T[d + 1][m] = (f16)v.y;
            T[d + 2][m] = (f16)v.z; T[d + 3][m] = (f16)v.w;
        }
        __syncthreads();
#pragma unroll
        for (int it = 0; it < 2; ++it) {
            const int d = (t >> 3) + it * 32, m = (t & 7) << 3;
            *(f16x8*)(O + (size_t)d * N_ + m0 + m) = *(const f16x8*)&T[d][m];
        }
        __syncthreads();
    }
}

// ---------------------------------------------------------------------------
// Per (b,n): pre-mix + mask + softmax + post-mix, in-place on attn (fp32).
// ---------------------------------------------------------------------------
__global__ __launch_bounds__(256) void mix_softmax_kernel(
    float* __restrict__ attn, const float* __restrict__ mask,
    const float* __restrict__ pl_w, const float* __restrict__ pl_b,
    const float* __restrict__ pw_w, const float* __restrict__ pw_b)
{
    const int n = blockIdx.x;
    const int b = blockIdx.y;
    const int tid = threadIdx.x;
    __shared__ float w1[64], w2[64], b1[8], b2[8];
    __shared__ float red[4][8];
    if (tid < 64) w1[tid] = pl_w[tid];
    else if (tid < 128) w2[tid - 64] = pw_w[tid - 64];
    else if (tid < 136) b1[tid - 128] = pl_b[tid - 128];
    else if (tid < 144) b2[tid - 136] = pw_b[tid - 136];
    __syncthreads();

    const int m0 = tid << 2;
    const size_t rowbase = ((size_t)(b * H_) * N_ + n) * N_ + m0;
    const size_t hstride = (size_t)N_ * N_;

    float s[8][4];
#pragma unroll
    for (int h = 0; h < 8; ++h) {
        float4 v = *(const float4*)(attn + rowbase + (size_t)h * hstride);
        s[h][0] = v.x; s[h][1] = v.y; s[h][2] = v.z; s[h][3] = v.w;
    }
    float4 mv = *(const float4*)(mask + b * N_ + m0);
    const float mk[4] = {(1.f - mv.x) * NEG_, (1.f - mv.y) * NEG_,
                         (1.f - mv.z) * NEG_, (1.f - mv.w) * NEG_};
    float a[8][4];
#pragma unroll
    for (int g = 0; g < 8; ++g)
#pragma unroll
        for (int j = 0; j < 4; ++j) a[g][j] = b1[g] + mk[j];
#pragma unroll
    for (int h = 0; h < 8; ++h)
#pragma unroll
        for (int g = 0; g < 8; ++g) {
            const float w = w1[g * 8 + h];
#pragma unroll
            for (int j = 0; j < 4; ++j) a[g][j] = fmaf(w, s[h][j], a[g][j]);
        }
    float mx[8];
#pragma unroll
    for (int g = 0; g < 8; ++g)
        mx[g] = fmaxf(fmaxf(a[g][0], a[g][1]), fmaxf(a[g][2], a[g][3]));
#pragma unroll
    for (int g = 0; g < 8; ++g)
        for (int off = 32; off; off >>= 1)
            mx[g] = fmaxf(mx[g], __shfl_xor(mx[g], off));
    const int wv = tid >> 6, ln = tid & 63;
    if (ln == 0) {
#pragma unroll
        for (int g = 0; g < 8; ++g) red[wv][g] = mx[g];
    }
    __syncthreads();
#pragma unroll
    for (int g = 0; g < 8; ++g)
        mx[g] = fmaxf(fmaxf(red[0][g], red[1][g]), fmaxf(red[2][g], red[3][g]));
    __syncthreads();
    float sm[8];
#pragma unroll
    for (int g = 0; g < 8; ++g) {
        float t = 0.f;
#pragma unroll
        for (int j = 0; j < 4; ++j) {
            a[g][j] = __expf(a[g][j] - mx[g]);
            t += a[g][j];
        }
        sm[g] = t;
    }
#pragma unroll
    for (int g = 0; g < 8; ++g)
        for (int off = 32; off; off >>= 1)
            sm[g] += __shfl_xor(sm[g], off);
    if (ln == 0) {
#pragma unroll
        for (int g = 0; g < 8; ++g) red[wv][g] = sm[g];
    }
    __syncthreads();
#pragma unroll
    for (int g = 0; g < 8; ++g) {
        const float inv = 1.f / (red[0][g] + red[1][g] + red[2][g] + red[3][g]);
#pragma unroll
        for (int j = 0; j < 4; ++j) a[g][j] *= inv;
    }
#pragma unroll
    for (int g = 0; g < 8; ++g) {
        float o[4] = {b2[g], b2[g], b2[g], b2[g]};
#pragma unroll
        for (int h = 0; h < 8; ++h) {
            const float w = w2[g * 8 + h];
#pragma unroll
            for (int j = 0; j < 4; ++j) o[j] = fmaf(w, a[h][j], o[j]);
        }
        *(float4*)(attn + rowbase + (size_t)g * hstride) = make_float4(o[0], o[1], o[2], o[3]);
    }
}

extern "C" void kernel_launch(void* const* d_in, const int* in_sizes, int n_in,
                              void* d_out, int out_size, void* d_ws, size_t ws_size,
                              hipStream_t stream)
{
    const float* x      = (const float*)d_in[0];
    const float* mask   = (const float*)d_in[1];
    const float* qkv_w  = (const float*)d_in[2];
    const float* qkv_b  = (const float*)d_in[3];
    const float* proj_w = (const float*)d_in[4];
    const float* proj_b = (const float*)d_in[5];
    const float* pl_w   = (const float*)d_in[6];
    const float* pl_b   = (const float*)d_in[7];
    const float* pw_w   = (const float*)d_in[8];
    const float* pw_b   = (const float*)d_in[9];

    float* out  = (float*)d_out;                       // [B,N,C]
    float* attn = out + (size_t)B_ * N_ * C_;          // [B,H,N,N]
    float* qkv  = (float*)d_ws;                        // 12,582,912 f (50.3 MB)
    float* out1 = qkv + (size_t)B_ * N_ * 3 * C_;      // 4,194,304 f (16.8 MB)
    f16*   vt   = (f16*)(out1 + (size_t)B_ * N_ * C_); // 4,194,304 h (8.4 MB)
    (void)in_sizes; (void)n_in; (void)out_size; (void)ws_size;

    // 1) qkv = x @ qkv_w^T + qkv_b          (8192 x 1536 x 512, f16 MFMA)
    k_qkv<<<dim3(QKVLD / 128, B_ * N_ / 128), 256, 0, stream>>>(x, qkv_w, qkv_b, qkv);

    // 2) V^T pack to f16 [b,h,d,m]
    pack_vt<<<dim3(B_ * H_), 256, 0, stream>>>(qkv, vt);

    // 3) raw scaled scores into d_out attn region
    k_scores<<<dim3(N_ / 128, N_ / 128, B_ * H_), 256, 0, stream>>>(qkv, attn);

    // 4) pre-mix + mask + softmax + post-mix, in place
    mix_softmax_kernel<<<dim3(N_, B_), 256, 0, stream>>>(attn, mask, pl_w, pl_b, pw_w, pw_b);

    // 5) out1 = attn2 @ V                   (per b,h; f16 MFMA)
    k_pv<<<dim3(1, N_ / 128, B_ * H_), 256, 0, stream>>>(attn, vt, out1);

    // 6) out = out1 @ proj_w^T + proj_b     (8192 x 512 x 512, f16 MFMA)
    k_proj<<<dim3(C_ / 128, B_ * N_ / 128), 256, 0, stream>>>(out1, proj_w, proj_b, out);
}